// Round 1
// baseline (187.802 us; speedup 1.0000x reference)
//
#include <hip/hip_runtime.h>

// out[b,c,i] += W[i]^2 * x[b,c,j] for each edge e=(i=iInd[e], j=jInd[e]); B=1.
// Strategy: transpose x [C,N] -> xt [N,C] so each edge touches contiguous
// 128B chunks; scatter-add with f32 atomics into outt [N,C]; transpose back.

#define TCH 32  // channel count (fixed by problem: CHANNELS=32)

__global__ void transpose_CN_to_NC(const float* __restrict__ x,
                                   float* __restrict__ xt, int N) {
    __shared__ float tile[32][33];
    const int n0 = blockIdx.x * 32;
    const int tx = threadIdx.x;   // 0..31
    const int ty = threadIdx.y;   // 0..31 (channel on load)
    const int n = n0 + tx;
    if (n < N) tile[ty][tx] = x[ty * N + n];        // coalesced along n
    __syncthreads();
    const int nw = n0 + ty;
    if (nw < N) xt[nw * TCH + tx] = tile[tx][ty];   // coalesced along c
}

__global__ void transpose_NC_to_CN(const float* __restrict__ xt,
                                   float* __restrict__ out, int N) {
    __shared__ float tile[32][33];
    const int n0 = blockIdx.x * 32;
    const int tx = threadIdx.x;
    const int ty = threadIdx.y;
    const int n = n0 + ty;
    if (n < N) tile[ty][tx] = xt[n * TCH + tx];     // coalesced along c
    __syncthreads();
    const int nr = n0 + tx;
    if (nr < N) out[ty * N + nr] = tile[tx][ty];    // coalesced along n
}

// One thread per (edge, channel). 32 lanes share an edge -> the xt gather is
// one contiguous 128B segment; atomics go to one contiguous 128B segment.
__global__ void edge_scatter_nc(const int* __restrict__ iInd,
                                const int* __restrict__ jInd,
                                const float* __restrict__ W,
                                const float* __restrict__ xt,
                                float* __restrict__ outt, int E) {
    const long long t = (long long)blockIdx.x * blockDim.x + threadIdx.x;
    const int e = (int)(t >> 5);
    const int c = (int)(t & 31);
    if (e < E) {
        const int i = iInd[e];
        const int j = jInd[e];
        const float w = W[i];
        const float v = w * w * xt[j * TCH + c];
        atomicAdd(&outt[i * TCH + c], v);
    }
}

// Fallback (ws too small): operate directly in [C,N] layout.
__global__ void edge_scatter_cn(const int* __restrict__ iInd,
                                const int* __restrict__ jInd,
                                const float* __restrict__ W,
                                const float* __restrict__ x,
                                float* __restrict__ out, int E, int N) {
    const long long t = (long long)blockIdx.x * blockDim.x + threadIdx.x;
    const int e = (int)(t >> 5);
    const int c = (int)(t & 31);
    if (e < E) {
        const int i = iInd[e];
        const int j = jInd[e];
        const float w = W[i];
        const float v = w * w * x[c * N + j];
        atomicAdd(&out[c * N + i], v);
    }
}

extern "C" void kernel_launch(void* const* d_in, const int* in_sizes, int n_in,
                              void* d_out, int out_size, void* d_ws, size_t ws_size,
                              hipStream_t stream) {
    const float* x    = (const float*)d_in[0];   // [1, C, N]
    const float* W    = (const float*)d_in[1];   // [N]
    const int*   iInd = (const int*)d_in[2];     // [E]
    const int*   jInd = (const int*)d_in[3];     // [E]

    const int N = in_sizes[1];
    const int E = in_sizes[2];

    float* out = (float*)d_out;

    const size_t buf_elems = (size_t)N * TCH;
    const size_t need = 2 * buf_elems * sizeof(float);

    const int scatter_threads = 256;
    const long long total = (long long)E * TCH;
    const int scatter_blocks = (int)((total + scatter_threads - 1) / scatter_threads);

    if (ws_size >= need) {
        float* xt   = (float*)d_ws;
        float* outt = xt + buf_elems;

        const int ntiles = (N + 31) / 32;
        dim3 tb(32, 32);
        transpose_CN_to_NC<<<ntiles, tb, 0, stream>>>(x, xt, N);
        hipMemsetAsync(outt, 0, buf_elems * sizeof(float), stream);
        edge_scatter_nc<<<scatter_blocks, scatter_threads, 0, stream>>>(
            iInd, jInd, W, xt, outt, E);
        transpose_NC_to_CN<<<ntiles, tb, 0, stream>>>(outt, out, N);
    } else {
        hipMemsetAsync(out, 0, (size_t)out_size * sizeof(float), stream);
        edge_scatter_cn<<<scatter_blocks, scatter_threads, 0, stream>>>(
            iInd, jInd, W, x, out, E, N);
    }
}